// Round 1
// baseline (533.538 us; speedup 1.0000x reference)
//
#include <hip/hip_runtime.h>

// Problem constants (match reference)
#define B 4
#define L 2048
#define C 64
#define R 8
#define NCH (B * C)        // 256 independent chains
#define T 64               // chunk length (timesteps per wave)
#define S (L / T)          // 32 chunks per chain
#define NCHUNK (NCH * S)   // 8192 chunk-waves

// Workspace layout (float2 = {re, im}):
//   sumA  : [NCHUNK][64]  chunk A-products        (4 MB)
//   sumY  : [NCHUNK][8]   chunk zero-carry scans  (0.5 MB)
//   carry : [NCHUNK][8]   incoming carry per chunk(0.5 MB)
// indexing: chunk id wg = s*NCH + n  (n = chain, fastest)

// Lane mapping within a wave: lane = i*8 + j  (i = row, j = col).
// P[i][j] lives in lane (i,j).  The running vector y is kept in
// "column-replicated" layout: lane (i,j) holds y[j] (same for all i).

__global__ __launch_bounds__(256) void k_summary(
    const float* __restrict__ Are, const float* __restrict__ Aim,
    const float* __restrict__ Xre, const float* __restrict__ Xim,
    float2* __restrict__ sumA, float2* __restrict__ sumY)
{
    const int wg   = (blockIdx.x * blockDim.x + threadIdx.x) >> 6; // global wave
    const int lane = threadIdx.x & 63;
    const int i = lane >> 3, j = lane & 7;
    const int s = wg >> 8;        // chunk index (NCH = 256)
    const int n = wg & (NCH - 1); // chain
    const int b = n >> 6, c = n & (C - 1);

    // P = identity
    float Pre = (i == j) ? 1.f : 0.f, Pim = 0.f;
    // y-hat (zero carry), column-replicated
    float yr = 0.f, yi = 0.f;

    long baseA = (((long)b * L + (long)s * T) * C + c) * (R * R);
    long baseX = (((long)b * L + (long)s * T) * C + c) * R;

    for (int tt = 0; tt < T; ++tt) {
        const float ar = Are[baseA + lane];
        const float ai = Aim[baseA + lane];
        const float xr = Xre[baseX + i];
        const float xi = Xim[baseX + i];
        baseA += (long)C * R * R;
        baseX += (long)C * R;

        // ---- matvec: y_new[i] = sum_j A[i][j]*y[j] + x[i]
        float pr = ar * yr - ai * yi;
        float pi = ar * yi + ai * yr;
        pr += __shfl_xor(pr, 1); pi += __shfl_xor(pi, 1);
        pr += __shfl_xor(pr, 2); pi += __shfl_xor(pi, 2);
        pr += __shfl_xor(pr, 4); pi += __shfl_xor(pi, 4);
        pr += xr; pi += xi;                 // row-replicated y_new[i]
        // transpose back to column-replicated: lane (i,j) <- y_new[j]
        yr = __shfl(pr, (j << 3) | i);
        yi = __shfl(pi, (j << 3) | i);

        // ---- matmul: Pnew[i][j] = sum_k A[i][k] * P[k][j]
        float nr = 0.f, ni = 0.f;
        #pragma unroll
        for (int k = 0; k < 8; ++k) {
            const float akr = __shfl(ar,  (i << 3) | k);
            const float aki = __shfl(ai,  (i << 3) | k);
            const float pkr = __shfl(Pre, (k << 3) | j);
            const float pki = __shfl(Pim, (k << 3) | j);
            nr += akr * pkr - aki * pki;
            ni += akr * pki + aki * pkr;
        }
        Pre = nr; Pim = ni;
    }

    sumA[(long)wg * 64 + lane] = make_float2(Pre, Pim);
    if (i == 0) sumY[wg * 8 + j] = make_float2(yr, yi);
}

__global__ __launch_bounds__(64) void k_carry(
    const float2* __restrict__ sumA, const float2* __restrict__ sumY,
    float2* __restrict__ carry)
{
    const int n = blockIdx.x;          // one wave per chain
    const int lane = threadIdx.x;
    const int i = lane >> 3, j = lane & 7;

    float yr = 0.f, yi = 0.f;          // carry into chunk 0 is zero
    for (int s = 0; s < S; ++s) {
        const int idx = s * NCH + n;
        if (i == 0) carry[idx * 8 + j] = make_float2(yr, yi);
        const float2 a  = sumA[(long)idx * 64 + lane];
        const float2 xb = sumY[idx * 8 + i];
        float pr = a.x * yr - a.y * yi;
        float pi = a.x * yi + a.y * yr;
        pr += __shfl_xor(pr, 1); pi += __shfl_xor(pi, 1);
        pr += __shfl_xor(pr, 2); pi += __shfl_xor(pi, 2);
        pr += __shfl_xor(pr, 4); pi += __shfl_xor(pi, 4);
        pr += xb.x; pi += xb.y;
        yr = __shfl(pr, (j << 3) | i);
        yi = __shfl(pi, (j << 3) | i);
    }
}

__global__ __launch_bounds__(256) void k_fixup(
    const float* __restrict__ Are, const float* __restrict__ Aim,
    const float* __restrict__ Xre, const float* __restrict__ Xim,
    const float2* __restrict__ carry, float* __restrict__ out)
{
    const int wgr  = (blockIdx.x * blockDim.x + threadIdx.x) >> 6;
    const int wg   = NCHUNK - 1 - wgr;   // reversed order for L3 reuse
    const int lane = threadIdx.x & 63;
    const int i = lane >> 3, j = lane & 7;
    const int s = wg >> 8;
    const int n = wg & (NCH - 1);
    const int b = n >> 6, c = n & (C - 1);

    const float2 cv = carry[wg * 8 + j]; // column-replicated carry
    float yr = cv.x, yi = cv.y;

    long baseA = (((long)b * L + (long)s * T) * C + c) * (R * R);
    long baseX = (((long)b * L + (long)s * T) * C + c) * R;
    long baseO = (((long)b * L + (long)s * T) * C + c) * (R * 2);

    for (int tt = 0; tt < T; ++tt) {
        const float ar = Are[baseA + lane];
        const float ai = Aim[baseA + lane];
        const float xr = Xre[baseX + i];
        const float xi = Xim[baseX + i];

        float pr = ar * yr - ai * yi;
        float pi = ar * yi + ai * yr;
        pr += __shfl_xor(pr, 1); pi += __shfl_xor(pi, 1);
        pr += __shfl_xor(pr, 2); pi += __shfl_xor(pi, 2);
        pr += __shfl_xor(pr, 4); pi += __shfl_xor(pi, 4);
        pr += xr; pi += xi;                 // y_new[i], row-replicated

        // lanes (i,0)/(i,1) write re/im -> out[b][t][c][i][0/1]
        if (j < 2) out[baseO + i * 2 + j] = (j == 0) ? pr : pi;

        yr = __shfl(pr, (j << 3) | i);
        yi = __shfl(pi, (j << 3) | i);

        baseA += (long)C * R * R;
        baseX += (long)C * R;
        baseO += (long)C * R * 2;
    }
}

extern "C" void kernel_launch(void* const* d_in, const int* in_sizes, int n_in,
                              void* d_out, int out_size, void* d_ws, size_t ws_size,
                              hipStream_t stream)
{
    const float* Are = (const float*)d_in[0];
    const float* Aim = (const float*)d_in[1];
    const float* Xre = (const float*)d_in[2];
    const float* Xim = (const float*)d_in[3];
    float* out = (float*)d_out;

    // workspace carve-up (needs ~5 MB)
    float2* sumA  = (float2*)d_ws;                       // NCHUNK*64 float2
    float2* sumY  = sumA + (long)NCHUNK * 64;            // NCHUNK*8  float2
    float2* carry = sumY + (long)NCHUNK * 8;             // NCHUNK*8  float2

    // Phase 1: chunk summaries (8192 waves, 4 waves/block)
    k_summary<<<NCHUNK / 4, 256, 0, stream>>>(Are, Aim, Xre, Xim, sumA, sumY);
    // Phase 2: carry scan (one wave per chain)
    k_carry<<<NCH, 64, 0, stream>>>(sumA, sumY, carry);
    // Phase 3: fixup + output write (reversed chunk order)
    k_fixup<<<NCHUNK / 4, 256, 0, stream>>>(Are, Aim, Xre, Xim, carry, out);
}

// Round 2
// 373.819 us; speedup vs baseline: 1.4273x; 1.4273x over previous
//
#include <hip/hip_runtime.h>

#define B 4
#define L 2048
#define C 64
#define R 8
#define NCH (B * C)      // 256 chains
#define TQ 64            // timesteps per chunk
#define S (L / TQ)       // 32 chunks per chain
#define GRP (NCH / 8)    // 32 chain-groups (8 chains per wave)

// Workspace (float2): sumP [S][NCH][8][8] (4 MB), sumQ [S][NCH][8] (0.5 MB),
// carry [S][NCH][8] (0.5 MB). Total 5 MB.
//
// Lane mapping everywhere: lane = c*8 + r  (c = chain-in-group, r = row).
// Phase 1 (backward): q += P @ x_t ; P = P @ A_t  => P = A_end..A_start,
// q = zero-carry chunk output. Row ownership: lane holds row r of P; the
// matmul consumes ROWS of A_t, broadcast-read from LDS (no shuffles).

// ---------------- Phase 1: chunk summaries ----------------
__global__ __launch_bounds__(64) void k_summary(
    const float* __restrict__ Are, const float* __restrict__ Aim,
    const float* __restrict__ Xre, const float* __restrict__ Xim,
    float2* __restrict__ sumP, float2* __restrict__ sumQ)
{
    __shared__ __align__(16) float sm[1152]; // Are[512] Aim[512] Xre[64] Xim[64]
    const int lane = threadIdx.x;
    const int c = lane >> 3, r = lane & 7;
    const int s = blockIdx.x >> 5;       // chunk
    const int g = blockIdx.x & 31;       // chain-group
    const int n0 = g * 8;
    const int b = n0 >> 6;
    const int cc0 = n0 & (C - 1);
    const int n = n0 + c;
    const int tbase = s * TQ;

    float Pre[8], Pim[8];
#pragma unroll
    for (int k = 0; k < 8; ++k) { Pre[k] = (k == r) ? 1.f : 0.f; Pim[k] = 0.f; }
    float qre = 0.f, qim = 0.f;

    float4 sa0, sa1, si0, si1; float sxr, sxi;   // pipeline set 0
    float4 ta0, ta1, ti0, ti1; float txr, txi;   // pipeline set 1

#define LOADSET1(t, A0, A1, I0, I1, XR, XI)                                    \
    {                                                                          \
        const int fb = (b * L + (t)) * C + cc0;                                \
        const float4* pA = (const float4*)(Are + (long)fb * 64) + lane * 2;    \
        const float4* pI = (const float4*)(Aim + (long)fb * 64) + lane * 2;    \
        A0 = pA[0]; A1 = pA[1]; I0 = pI[0]; I1 = pI[1];                        \
        XR = Xre[(long)fb * 8 + lane]; XI = Xim[(long)fb * 8 + lane];          \
    }

#define STAGESET1(A0, A1, I0, I1, XR, XI)                                      \
    {                                                                          \
        float4* s4 = (float4*)sm;                                              \
        s4[lane * 2] = A0; s4[lane * 2 + 1] = A1;                              \
        s4[128 + lane * 2] = I0; s4[128 + lane * 2 + 1] = I1;                  \
        sm[1024 + lane] = XR; sm[1088 + lane] = XI;                            \
    }

#define COMPUTE_STEP1()                                                        \
    {                                                                          \
        float xr[8], xi[8];                                                    \
        *(float4*)&xr[0] = *(const float4*)(sm + 1024 + c * 8);                \
        *(float4*)&xr[4] = *(const float4*)(sm + 1024 + c * 8 + 4);            \
        *(float4*)&xi[0] = *(const float4*)(sm + 1088 + c * 8);                \
        *(float4*)&xi[4] = *(const float4*)(sm + 1088 + c * 8 + 4);            \
        _Pragma("unroll")                                                      \
        for (int k = 0; k < 8; ++k) {                                          \
            qre += Pre[k] * xr[k] - Pim[k] * xi[k];                            \
            qim += Pre[k] * xi[k] + Pim[k] * xr[k];                            \
        }                                                                      \
        float Nre[8], Nim[8];                                                  \
        _Pragma("unroll")                                                      \
        for (int j = 0; j < 8; ++j) { Nre[j] = 0.f; Nim[j] = 0.f; }            \
        _Pragma("unroll")                                                      \
        for (int k = 0; k < 8; ++k) {                                          \
            float er[8], ei[8];                                                \
            *(float4*)&er[0] = *(const float4*)(sm + c * 64 + k * 8);          \
            *(float4*)&er[4] = *(const float4*)(sm + c * 64 + k * 8 + 4);      \
            *(float4*)&ei[0] = *(const float4*)(sm + 512 + c * 64 + k * 8);    \
            *(float4*)&ei[4] = *(const float4*)(sm + 512 + c * 64 + k * 8 + 4);\
            const float pr = Pre[k], pi = Pim[k];                              \
            _Pragma("unroll")                                                  \
            for (int j = 0; j < 8; ++j) {                                      \
                Nre[j] += pr * er[j] - pi * ei[j];                             \
                Nim[j] += pr * ei[j] + pi * er[j];                             \
            }                                                                  \
        }                                                                      \
        _Pragma("unroll")                                                      \
        for (int k = 0; k < 8; ++k) { Pre[k] = Nre[k]; Pim[k] = Nim[k]; }      \
    }

    LOADSET1(tbase + TQ - 1, sa0, sa1, si0, si1, sxr, sxi);
    LOADSET1(tbase + TQ - 2, ta0, ta1, ti0, ti1, txr, txi);

#pragma unroll 1
    for (int tt = TQ - 1; tt >= 1; tt -= 2) {
        STAGESET1(sa0, sa1, si0, si1, sxr, sxi);
        if (tt >= 3) LOADSET1(tbase + tt - 2, sa0, sa1, si0, si1, sxr, sxi);
        COMPUTE_STEP1();
        STAGESET1(ta0, ta1, ti0, ti1, txr, txi);
        if (tt >= 3) LOADSET1(tbase + tt - 3, ta0, ta1, ti0, ti1, txr, txi);
        COMPUTE_STEP1();
    }

    // store P row r (8 complex) and q
    float4* gp = (float4*)(sumP + ((long)(s * 256 + n) * 8 + r) * 8);
    gp[0] = make_float4(Pre[0], Pim[0], Pre[1], Pim[1]);
    gp[1] = make_float4(Pre[2], Pim[2], Pre[3], Pim[3]);
    gp[2] = make_float4(Pre[4], Pim[4], Pre[5], Pim[5]);
    gp[3] = make_float4(Pre[6], Pim[6], Pre[7], Pim[7]);
    sumQ[(long)(s * 256 + n) * 8 + r] = make_float2(qre, qim);
}

// ---------------- Phase 2: carry scan over chunks ----------------
__global__ __launch_bounds__(64) void k_carry(
    const float2* __restrict__ sumP, const float2* __restrict__ sumQ,
    float2* __restrict__ carry)
{
    __shared__ __align__(16) float cb[128];
    const int lane = threadIdx.x;
    const int c = lane >> 3, r = lane & 7;
    const int n = blockIdx.x * 8 + c;

    float yr = 0.f, yi = 0.f;    // carry into chunk 0 is zero
#pragma unroll 1
    for (int s = 0; s < S; ++s) {
        const long base = (long)(s * 256 + n) * 8;
        carry[base + r] = make_float2(yr, yi);
        // replicate carry vector within chain group via LDS
        cb[lane * 2] = yr; cb[lane * 2 + 1] = yi;
        float yvr[8], yvi[8];
        {
            float4 u0 = *(const float4*)(cb + c * 16);
            float4 u1 = *(const float4*)(cb + c * 16 + 4);
            float4 u2 = *(const float4*)(cb + c * 16 + 8);
            float4 u3 = *(const float4*)(cb + c * 16 + 12);
            yvr[0]=u0.x; yvi[0]=u0.y; yvr[1]=u0.z; yvi[1]=u0.w;
            yvr[2]=u1.x; yvi[2]=u1.y; yvr[3]=u1.z; yvi[3]=u1.w;
            yvr[4]=u2.x; yvi[4]=u2.y; yvr[5]=u2.z; yvi[5]=u2.w;
            yvr[6]=u3.x; yvi[6]=u3.y; yvr[7]=u3.z; yvi[7]=u3.w;
        }
        const float4* prow = (const float4*)(sumP + (base + r) * 8);
        float4 p0 = prow[0], p1 = prow[1], p2 = prow[2], p3 = prow[3];
        float prr[8], pri[8];
        prr[0]=p0.x; pri[0]=p0.y; prr[1]=p0.z; pri[1]=p0.w;
        prr[2]=p1.x; pri[2]=p1.y; prr[3]=p1.z; pri[3]=p1.w;
        prr[4]=p2.x; pri[4]=p2.y; prr[5]=p2.z; pri[5]=p2.w;
        prr[6]=p3.x; pri[6]=p3.y; prr[7]=p3.z; pri[7]=p3.w;
        float2 qv = sumQ[base + r];
        float nr = qv.x, ni = qv.y;
#pragma unroll
        for (int k = 0; k < 8; ++k) {
            nr += prr[k] * yvr[k] - pri[k] * yvi[k];
            ni += prr[k] * yvi[k] + pri[k] * yvr[k];
        }
        yr = nr; yi = ni;
    }
}

// ---------------- Phase 3: fixup + output ----------------
__global__ __launch_bounds__(64) void k_fixup(
    const float* __restrict__ Are, const float* __restrict__ Aim,
    const float* __restrict__ Xre, const float* __restrict__ Xim,
    const float2* __restrict__ carry, float2* __restrict__ out)
{
    __shared__ __align__(16) float sm[1024]; // Are[512] Aim[512]
    __shared__ __align__(16) float cb[128];
    const int lane = threadIdx.x;
    const int c = lane >> 3, r = lane & 7;
    const int blk = (int)gridDim.x - 1 - (int)blockIdx.x;  // reversed for L3 reuse
    const int s = blk >> 5;
    const int g = blk & 31;
    const int n0 = g * 8;
    const int b = n0 >> 6;
    const int cc0 = n0 & (C - 1);
    const int n = n0 + c;
    const int tbase = s * TQ;

    float yvr[8], yvi[8];
    {
        const float4* cv = (const float4*)(carry + (long)(s * 256 + n) * 8);
        float4 w0 = cv[0], w1 = cv[1], w2 = cv[2], w3 = cv[3];
        yvr[0]=w0.x; yvi[0]=w0.y; yvr[1]=w0.z; yvi[1]=w0.w;
        yvr[2]=w1.x; yvi[2]=w1.y; yvr[3]=w1.z; yvi[3]=w1.w;
        yvr[4]=w2.x; yvi[4]=w2.y; yvr[5]=w2.z; yvi[5]=w2.w;
        yvr[6]=w3.x; yvi[6]=w3.y; yvr[7]=w3.z; yvi[7]=w3.w;
    }

    float4 sa0, sa1, si0, si1; float sxr, sxi;
    float4 ta0, ta1, ti0, ti1; float txr, txi;

#define LOADSET3(t, A0, A1, I0, I1, XR, XI)                                    \
    {                                                                          \
        const int fb = (b * L + (t)) * C + cc0;                                \
        const float4* pA = (const float4*)(Are + (long)fb * 64) + lane * 2;    \
        const float4* pI = (const float4*)(Aim + (long)fb * 64) + lane * 2;    \
        A0 = pA[0]; A1 = pA[1]; I0 = pI[0]; I1 = pI[1];                        \
        XR = Xre[(long)fb * 8 + lane]; XI = Xim[(long)fb * 8 + lane];          \
    }

#define STAGESET3(A0, A1, I0, I1)                                              \
    {                                                                          \
        float4* s4 = (float4*)sm;                                              \
        s4[lane * 2] = A0; s4[lane * 2 + 1] = A1;                              \
        s4[128 + lane * 2] = I0; s4[128 + lane * 2 + 1] = I1;                  \
    }

#define FIX_STEP(t, XR_, XI_)                                                  \
    {                                                                          \
        float ar[8], ai[8];                                                    \
        *(float4*)&ar[0] = *(const float4*)(sm + c * 64 + r * 8);              \
        *(float4*)&ar[4] = *(const float4*)(sm + c * 64 + r * 8 + 4);          \
        *(float4*)&ai[0] = *(const float4*)(sm + 512 + c * 64 + r * 8);        \
        *(float4*)&ai[4] = *(const float4*)(sm + 512 + c * 64 + r * 8 + 4);    \
        float nr = XR_, ni = XI_;                                              \
        _Pragma("unroll")                                                      \
        for (int k = 0; k < 8; ++k) {                                          \
            nr += ar[k] * yvr[k] - ai[k] * yvi[k];                             \
            ni += ar[k] * yvi[k] + ai[k] * yvr[k];                             \
        }                                                                      \
        const int fb = (b * L + (t)) * C + cc0;                                \
        out[(long)fb * 8 + lane] = make_float2(nr, ni);                        \
        cb[lane * 2] = nr; cb[lane * 2 + 1] = ni;                              \
        float4 u0 = *(const float4*)(cb + c * 16);                             \
        float4 u1 = *(const float4*)(cb + c * 16 + 4);                         \
        float4 u2 = *(const float4*)(cb + c * 16 + 8);                         \
        float4 u3 = *(const float4*)(cb + c * 16 + 12);                        \
        yvr[0]=u0.x; yvi[0]=u0.y; yvr[1]=u0.z; yvi[1]=u0.w;                    \
        yvr[2]=u1.x; yvi[2]=u1.y; yvr[3]=u1.z; yvi[3]=u1.w;                    \
        yvr[4]=u2.x; yvi[4]=u2.y; yvr[5]=u2.z; yvi[5]=u2.w;                    \
        yvr[6]=u3.x; yvi[6]=u3.y; yvr[7]=u3.z; yvi[7]=u3.w;                    \
    }

    LOADSET3(tbase + 0, sa0, sa1, si0, si1, sxr, sxi);
    LOADSET3(tbase + 1, ta0, ta1, ti0, ti1, txr, txi);

#pragma unroll 1
    for (int tt = 0; tt < TQ; tt += 2) {
        STAGESET3(sa0, sa1, si0, si1);
        float xcr = sxr, xci = sxi;
        if (tt + 2 < TQ) LOADSET3(tbase + tt + 2, sa0, sa1, si0, si1, sxr, sxi);
        FIX_STEP(tbase + tt, xcr, xci);
        STAGESET3(ta0, ta1, ti0, ti1);
        float xdr = txr, xdi = txi;
        if (tt + 3 < TQ) LOADSET3(tbase + tt + 3, ta0, ta1, ti0, ti1, txr, txi);
        FIX_STEP(tbase + tt + 1, xdr, xdi);
    }
}

extern "C" void kernel_launch(void* const* d_in, const int* in_sizes, int n_in,
                              void* d_out, int out_size, void* d_ws, size_t ws_size,
                              hipStream_t stream)
{
    const float* Are = (const float*)d_in[0];
    const float* Aim = (const float*)d_in[1];
    const float* Xre = (const float*)d_in[2];
    const float* Xim = (const float*)d_in[3];
    float2* out = (float2*)d_out;

    float2* sumP  = (float2*)d_ws;                    // S*NCH*64 float2 (4 MB)
    float2* sumQ  = sumP + (long)S * NCH * 64;        // S*NCH*8  float2 (0.5 MB)
    float2* carry = sumQ + (long)S * NCH * 8;         // S*NCH*8  float2 (0.5 MB)

    k_summary<<<S * GRP, 64, 0, stream>>>(Are, Aim, Xre, Xim, sumP, sumQ);
    k_carry<<<NCH / 8, 64, 0, stream>>>(sumP, sumQ, carry);
    k_fixup<<<S * GRP, 64, 0, stream>>>(Are, Aim, Xre, Xim, carry, out);
}